// Round 3
// baseline (361.731 us; speedup 1.0000x reference)
//
#include <hip/hip_runtime.h>

typedef __bf16 bf16;
typedef __bf16 bf16x8 __attribute__((ext_vector_type(8)));
typedef __bf16 bf16x4 __attribute__((ext_vector_type(4)));
typedef float  f32x4  __attribute__((ext_vector_type(4)));

#define BN_EPS 1e-5f

// Fragment-linear offset for MFMA B-operand matrix [N][K] (16x16x32 tiles):
// tile = (k/32)*ntiles + n/16 ; within tile: lane = ((k%32)/8)*16 + n%16, elem = k%8
__device__ __host__ __forceinline__ size_t frag_off(int n, int k, int ntiles) {
  return ((size_t)((k >> 5) * ntiles + (n >> 4)) << 9)
       + (size_t)((((k >> 3) & 3) << 4) + (n & 15)) * 8 + (k & 7);
}

// ---------------- prep kernels: fold BN, cast to bf16, swizzle to fragment layout ----------------

__global__ void prep_w1main(const float* __restrict__ l1w, const float* __restrict__ l1g, const float* __restrict__ l1v,
                            const float* __restrict__ g1w, const float* __restrict__ g1g, const float* __restrict__ g1v,
                            bf16* __restrict__ W1f) {
  int gid = blockIdx.x * blockDim.x + threadIdx.x;   // 512*1024
  int n = gid >> 10, k = gid & 1023;
  float s, w;
  if (n < 256) { s = l1g[n] * rsqrtf(l1v[n] + BN_EPS); w = l1w[(size_t)n * 1024 + k]; }
  else { int nn = n - 256; s = g1g[nn] * rsqrtf(g1v[nn] + BN_EPS); w = g1w[(size_t)nn * 1024 + k]; }
  W1f[frag_off(n, k, 32)] = (bf16)(w * s);
}

// tail columns 1024..1087 of W1cat = (s*W1) @ [cw | cb | 0], plus b1cat
__global__ void prep_w1tail(const float* __restrict__ l1w, const float* __restrict__ l1b, const float* __restrict__ l1g,
                            const float* __restrict__ l1be, const float* __restrict__ l1m, const float* __restrict__ l1v,
                            const float* __restrict__ g1w, const float* __restrict__ g1b, const float* __restrict__ g1g,
                            const float* __restrict__ g1be, const float* __restrict__ g1m, const float* __restrict__ g1v,
                            const float* __restrict__ cw, const float* __restrict__ cb,
                            bf16* __restrict__ W1f, float* __restrict__ b1cat) {
  int gid = blockIdx.x * blockDim.x + threadIdx.x;   // 512*64
  int n = gid >> 6, kc = gid & 63;
  const float* wrow; float s, bb, mm, be;
  if (n < 256) { s = l1g[n] * rsqrtf(l1v[n] + BN_EPS); wrow = l1w + (size_t)n * 1024;
                 bb = l1b[n]; mm = l1m[n]; be = l1be[n]; }
  else { int nn = n - 256; s = g1g[nn] * rsqrtf(g1v[nn] + BN_EPS); wrow = g1w + (size_t)nn * 1024;
         bb = g1b[nn]; mm = g1m[nn]; be = g1be[nn]; }
  float val = 0.f;
  if (kc < 49) {
    for (int j = 0; j < 1024; ++j) {
      float cv = (kc < 48) ? cw[(size_t)j * 48 + kc] : cb[j];
      val += wrow[j] * cv;
    }
    val *= s;
  }
  W1f[frag_off(n, 1024 + kc, 32)] = (bf16)val;
  if (kc == 0) b1cat[n] = s * (bb - mm) + be;
}

__global__ void prep_w2(const float* __restrict__ l2w, const float* __restrict__ l2b, const float* __restrict__ l2g,
                        const float* __restrict__ l2be, const float* __restrict__ l2m, const float* __restrict__ l2v,
                        const float* __restrict__ g2w, const float* __restrict__ g2b, const float* __restrict__ g2g,
                        const float* __restrict__ g2be, const float* __restrict__ g2m, const float* __restrict__ g2v,
                        bf16* __restrict__ W2f, float* __restrict__ b2sum) {
  int gid = blockIdx.x * blockDim.x + threadIdx.x;   // 1024*512
  int n = gid >> 9, k = gid & 511;
  float w;
  if (k < 256) { float s = l2g[n] * rsqrtf(l2v[n] + BN_EPS); w = l2w[(size_t)n * 256 + k] * s; }
  else { float s = g2g[n] * rsqrtf(g2v[n] + BN_EPS); w = g2w[(size_t)n * 256 + (k - 256)] * s; }
  W2f[frag_off(n, k, 64)] = (bf16)w;
  if (k == 0) {
    float sl = l2g[n] * rsqrtf(l2v[n] + BN_EPS), sg = g2g[n] * rsqrtf(g2v[n] + BN_EPS);
    b2sum[n] = sl * (l2b[n] - l2m[n]) + l2be[n] + sg * (g2b[n] - g2m[n]) + g2be[n];
  }
}

__global__ void prep_cwf(const float* __restrict__ cw, const float* __restrict__ cb, bf16* __restrict__ CWf) {
  int gid = blockIdx.x * blockDim.x + threadIdx.x;   // 1024*64
  int n = gid >> 6, kc = gid & 63;
  float v = (kc < 48) ? cw[(size_t)n * 48 + kc] : (kc == 48 ? cb[n] : 0.f);
  CWf[frag_off(n, kc, 64)] = (bf16)v;
}

__global__ void prep_f1f(const float* __restrict__ fw1, bf16* __restrict__ F1f) {
  int gid = blockIdx.x * blockDim.x + threadIdx.x;   // 256*2048
  int n = gid >> 11, k = gid & 2047;
  F1f[frag_off(n, k, 16)] = (bf16)fw1[(size_t)n * 2048 + k];
}

// ---------------- main fused kernel: M=64 rows, pipelined slices -> GEMM1 -> chunked GEMM2+combine ----------------

__global__ __launch_bounds__(512, 2)
void fused_main(const float* __restrict__ name1, const float* __restrict__ type1, const float* __restrict__ coor1,
                const float* __restrict__ name2, const float* __restrict__ type2, const float* __restrict__ coor2,
                const bf16* __restrict__ W1f, const bf16* __restrict__ W2f, const bf16* __restrict__ CWf,
                const float* __restrict__ b1cat, const float* __restrict__ b2sum,
                bf16* __restrict__ r_ws) {
  const int t = blockIdx.y;
  const float* __restrict__ name = t ? name2 : name1;
  const float* __restrict__ typ  = t ? type2 : type1;
  const float* __restrict__ coor = t ? coor2 : coor1;
  const int b0 = blockIdx.x * 64;
  const int tid = threadIdx.x;
  const int lane = tid & 63;
  const int wv = tid >> 6;
  const int arow = lane & 15;
  const int q    = lane >> 4;
  const int kgrp = q << 3;
  const int srow = tid >> 3, scg = tid & 7;   // staging map: 64 rows x 8 col-groups

  __shared__ bf16 Esl[4][64][136];  // 4 rotating k-slice regions (128 k each), 69,632 B
  __shared__ bf16 Hs[64][514];      // relu(GEMM1) [hL|hG], 65,792 B
  __shared__ bf16 Ct[64][72];       // [coor | 1 | 0] tail, 9,216 B   (total 144,640 B)

  // ---- stage Ct once ----
  {
    const float4* coor4 = reinterpret_cast<const float4*>(coor + (size_t)(b0 + srow) * 48);
    #pragma unroll
    for (int v = 0; v < 2; ++v) {
      int c4 = v * 8 + scg;
      float4 cv;
      if (c4 < 12)       cv = coor4[c4];
      else if (c4 == 12) cv = make_float4(1.f, 0.f, 0.f, 0.f);
      else               cv = make_float4(0.f, 0.f, 0.f, 0.f);
      bf16x4 e; e[0] = (bf16)cv.x; e[1] = (bf16)cv.y; e[2] = (bf16)cv.z; e[3] = (bf16)cv.w;
      *reinterpret_cast<bf16x4*>(&Ct[srow][c4 * 4]) = e;
    }
  }

  // ---- GEMM1 over 8 slices of 128 k, 4-region rotation, raw-barrier pipeline ----
  const float4* name4 = reinterpret_cast<const float4*>(name);
  const float4* typ4  = reinterpret_cast<const float4*>(typ);
  float4 nA[4], tA[4], nB[4], tB[4];

  auto LOADSL = [&](int i, float4 (&nv)[4], float4 (&tv)[4]) {
    size_t base = (size_t)(b0 + srow) * 256 + (size_t)i * 32 + scg;
    #pragma unroll
    for (int v = 0; v < 4; ++v) { nv[v] = name4[base + v * 8]; tv[v] = typ4[base + v * 8]; }
  };
  auto WRITESL = [&](int i, float4 (&nv)[4], float4 (&tv)[4]) {
    #pragma unroll
    for (int v = 0; v < 4; ++v) {
      bf16x4 e;
      e[0] = (bf16)(nv[v].x + tv[v].x); e[1] = (bf16)(nv[v].y + tv[v].y);
      e[2] = (bf16)(nv[v].z + tv[v].z); e[3] = (bf16)(nv[v].w + tv[v].w);
      *reinterpret_cast<bf16x4*>(&Esl[i & 3][srow][v * 32 + scg * 4]) = e;
    }
  };

  LOADSL(0, nA, tA);
  LOADSL(1, nB, tB);

  f32x4 acc1[4][4] = {};
  #pragma unroll 1
  for (int i = 0; i < 8; ++i) {
    if (i & 1) { WRITESL(i, nB, tB); if (i + 2 < 8) LOADSL(i + 2, nB, tB); }
    else       { WRITESL(i, nA, tA); if (i + 2 < 8) LOADSL(i + 2, nA, tA); }
    __builtin_amdgcn_sched_barrier(0);
    asm volatile("s_waitcnt lgkmcnt(0)" ::: "memory");
    __builtin_amdgcn_s_barrier();
    __builtin_amdgcn_sched_barrier(0);
    #pragma unroll
    for (int ks2 = 0; ks2 < 4; ++ks2) {
      int kk = i * 4 + ks2;
      bf16x8 a[4];
      #pragma unroll
      for (int m = 0; m < 4; ++m)
        a[m] = *reinterpret_cast<const bf16x8*>(&Esl[i & 3][m * 16 + arow][ks2 * 32 + kgrp]);
      #pragma unroll
      for (int u = 0; u < 4; ++u) {
        bf16x8 b = *reinterpret_cast<const bf16x8*>(W1f + (((size_t)(kk * 32 + wv * 4 + u)) << 9) + lane * 8);
        #pragma unroll
        for (int m = 0; m < 4; ++m)
          acc1[m][u] = __builtin_amdgcn_mfma_f32_16x16x32_bf16(a[m], b, acc1[m][u], 0, 0, 0);
      }
    }
  }
  // tail k-steps (k 1024..1087) from Ct
  #pragma unroll
  for (int j = 0; j < 2; ++j) {
    int kk = 32 + j;
    bf16x8 a[4];
    #pragma unroll
    for (int m = 0; m < 4; ++m)
      a[m] = *reinterpret_cast<const bf16x8*>(&Ct[m * 16 + arow][j * 32 + kgrp]);
    #pragma unroll
    for (int u = 0; u < 4; ++u) {
      bf16x8 b = *reinterpret_cast<const bf16x8*>(W1f + (((size_t)(kk * 32 + wv * 4 + u)) << 9) + lane * 8);
      #pragma unroll
      for (int m = 0; m < 4; ++m)
        acc1[m][u] = __builtin_amdgcn_mfma_f32_16x16x32_bf16(a[m], b, acc1[m][u], 0, 0, 0);
    }
  }

  // ---- H = relu(GEMM1 + b1cat) ----
  #pragma unroll
  for (int u = 0; u < 4; ++u) {
    int col = (wv * 4 + u) * 16 + arow;
    float bb = b1cat[col];
    #pragma unroll
    for (int m = 0; m < 4; ++m) {
      #pragma unroll
      for (int i2 = 0; i2 < 4; ++i2) {
        int row = m * 16 + q * 4 + i2;
        Hs[row][col] = (bf16)fmaxf(acc1[m][u][i2] + bb, 0.f);
      }
    }
  }
  __syncthreads();

  // ---- GEMM2 + combine, 4 n-chunks of 256 cols ----
  bf16 (*Rpack)[264] = reinterpret_cast<bf16 (*)[264]>(&Esl[0][0][0]);  // 33,792 B overlay on Esl
  #pragma unroll 1
  for (int nc = 0; nc < 4; ++nc) {
    f32x4 acc2[4][2] = {};
    #pragma unroll 4
    for (int ks = 0; ks < 16; ++ks) {
      bf16x8 a[4];
      #pragma unroll
      for (int m = 0; m < 4; ++m)
        a[m] = *reinterpret_cast<const bf16x8*>(&Hs[m * 16 + arow][ks * 32 + kgrp]);
      #pragma unroll
      for (int uu = 0; uu < 2; ++uu) {
        bf16x8 b = *reinterpret_cast<const bf16x8*>(W2f + (((size_t)(ks * 64 + nc * 16 + wv * 2 + uu)) << 9) + lane * 8);
        #pragma unroll
        for (int m = 0; m < 4; ++m)
          acc2[m][uu] = __builtin_amdgcn_mfma_f32_16x16x32_bf16(a[m], b, acc2[m][uu], 0, 0, 0);
      }
    }
    // c-tile for this chunk via 2-step MFMA
    f32x4 cacc[4][2] = {};
    #pragma unroll
    for (int j = 0; j < 2; ++j) {
      bf16x8 a[4];
      #pragma unroll
      for (int m = 0; m < 4; ++m)
        a[m] = *reinterpret_cast<const bf16x8*>(&Ct[m * 16 + arow][j * 32 + kgrp]);
      #pragma unroll
      for (int uu = 0; uu < 2; ++uu) {
        bf16x8 b = *reinterpret_cast<const bf16x8*>(CWf + (((size_t)(j * 64 + nc * 16 + wv * 2 + uu)) << 9) + lane * 8);
        #pragma unroll
        for (int m = 0; m < 4; ++m)
          cacc[m][uu] = __builtin_amdgcn_mfma_f32_16x16x32_bf16(a[m], b, cacc[m][uu], 0, 0, 0);
      }
    }
    // combine: wei = sigmoid(x), r = 2e + 2*wei*(c-e); e reloaded from f32 inputs
    #pragma unroll
    for (int uu = 0; uu < 2; ++uu) {
      int col = (nc * 16 + wv * 2 + uu) * 16 + arow;
      float b2 = b2sum[col];
      #pragma unroll
      for (int m = 0; m < 4; ++m) {
        #pragma unroll
        for (int i2 = 0; i2 < 4; ++i2) {
          int row = m * 16 + q * 4 + i2;
          float x = acc2[m][uu][i2] + b2;
          float wei = 1.f / (1.f + __expf(-x));
          size_t off = (size_t)(b0 + row) * 1024 + col;
          float e = name[off] + typ[off];
          float cv = cacc[m][uu][i2];
          Rpack[row][col - nc * 256] = (bf16)(2.f * e + 2.f * wei * (cv - e));
        }
      }
    }
    __syncthreads();
    // coalesced chunk writeout
    #pragma unroll
    for (int g = 0; g < 4; ++g) {
      int f = g * 512 + tid;
      int row = f >> 5, colg = f & 31;
      *reinterpret_cast<bf16x8*>(r_ws + (size_t)(b0 + row) * 2048 + (size_t)t * 1024 + nc * 256 + colg * 8) =
        *reinterpret_cast<const bf16x8*>(&Rpack[row][colg * 8]);
    }
    __syncthreads();
  }
}

// ---------------- final kernel: out = sigmoid(relu(r@fw1T+fb1)@fw2T+fb2), M=64, 2 blocks/CU ----------------

__global__ __launch_bounds__(512, 4)
void fused_final(const bf16* __restrict__ r_ws, const bf16* __restrict__ F1f,
                 const float* __restrict__ fb1, const float* __restrict__ fw2,
                 const float* __restrict__ fb2, float* __restrict__ out) {
  const int b0 = blockIdx.x * 64;
  const int tid = threadIdx.x;
  const int lane = tid & 63;
  const int wv = tid >> 6;
  const int arow = lane & 15;
  const int q    = lane >> 4;
  const int kgrp = q << 3;

  __shared__ bf16 RT[2][64][264];   // 67,584 B -> 2 blocks/CU
  float (*H2)[260] = reinterpret_cast<float (*)[260]>(&RT[0][0][0]);  // 66,560 B overlay

  bf16x8 sv[4];
  auto SLOAD = [&](int kc) {
    #pragma unroll
    for (int g = 0; g < 4; ++g) {
      int f = g * 512 + tid;
      int row = f >> 5, colg = f & 31;
      sv[g] = *reinterpret_cast<const bf16x8*>(r_ws + (size_t)(b0 + row) * 2048 + kc * 256 + colg * 8);
    }
  };
  auto SWRITE = [&](int buf) {
    #pragma unroll
    for (int g = 0; g < 4; ++g) {
      int f = g * 512 + tid;
      int row = f >> 5, colg = f & 31;
      *reinterpret_cast<bf16x8*>(&RT[buf][row][colg * 8]) = sv[g];
    }
  };

  SLOAD(0); SWRITE(0);
  __syncthreads();

  f32x4 acc[4][2] = {};
  #pragma unroll 1
  for (int kc = 0; kc < 8; ++kc) {
    if (kc < 7) SLOAD(kc + 1);          // issue HBM loads early (T14)
    #pragma unroll
    for (int ks = 0; ks < 8; ++ks) {
      int ksg = kc * 8 + ks;
      bf16x8 a[4];
      #pragma unroll
      for (int m = 0; m < 4; ++m)
        a[m] = *reinterpret_cast<const bf16x8*>(&RT[kc & 1][m * 16 + arow][ks * 32 + kgrp]);
      #pragma unroll
      for (int u = 0; u < 2; ++u) {
        bf16x8 b = *reinterpret_cast<const bf16x8*>(F1f + (((size_t)(ksg * 16 + wv * 2 + u)) << 9) + lane * 8);
        #pragma unroll
        for (int m = 0; m < 4; ++m)
          acc[m][u] = __builtin_amdgcn_mfma_f32_16x16x32_bf16(a[m], b, acc[m][u], 0, 0, 0);
      }
    }
    if (kc < 7) SWRITE((kc + 1) & 1);   // ds_write late; target buffer's readers finished last iter
    __syncthreads();
  }

  #pragma unroll
  for (int u = 0; u < 2; ++u) {
    int col = (wv * 2 + u) * 16 + arow;
    float bb = fb1[col];
    #pragma unroll
    for (int m = 0; m < 4; ++m) {
      #pragma unroll
      for (int i2 = 0; i2 < 4; ++i2) {
        int row = m * 16 + q * 4 + i2;
        H2[row][col] = fmaxf(acc[m][u][i2] + bb, 0.f);
      }
    }
  }
  __syncthreads();

  int row = tid >> 3, sub = tid & 7;
  float p = 0.f;
  #pragma unroll
  for (int c = 0; c < 32; ++c) p += H2[row][sub * 32 + c] * fw2[sub * 32 + c];
  p += __shfl_xor(p, 1, 8);
  p += __shfl_xor(p, 2, 8);
  p += __shfl_xor(p, 4, 8);
  if (sub == 0) out[b0 + row] = 1.f / (1.f + __expf(-(p + fb2[0])));
}

// ---------------- launcher ----------------

extern "C" void kernel_launch(void* const* d_in, const int* in_sizes, int n_in,
                              void* d_out, int out_size, void* d_ws, size_t ws_size,
                              hipStream_t stream) {
  const float* name1 = (const float*)d_in[0];
  const float* type1 = (const float*)d_in[1];
  const float* coor1 = (const float*)d_in[2];
  const float* name2 = (const float*)d_in[3];
  const float* type2 = (const float*)d_in[4];
  const float* coor2 = (const float*)d_in[5];
  const float* cw    = (const float*)d_in[6];
  const float* cb    = (const float*)d_in[7];
  const float* l1w = (const float*)d_in[8];  const float* l1b = (const float*)d_in[9];
  const float* l1g = (const float*)d_in[10]; const float* l1be = (const float*)d_in[11];
  const float* l1m = (const float*)d_in[12]; const float* l1v = (const float*)d_in[13];
  const float* l2w = (const float*)d_in[14]; const float* l2b = (const float*)d_in[15];
  const float* l2g = (const float*)d_in[16]; const float* l2be = (const float*)d_in[17];
  const float* l2m = (const float*)d_in[18]; const float* l2v = (const float*)d_in[19];
  const float* g1w = (const float*)d_in[20]; const float* g1b = (const float*)d_in[21];
  const float* g1g = (const float*)d_in[22]; const float* g1be = (const float*)d_in[23];
  const float* g1m = (const float*)d_in[24]; const float* g1v = (const float*)d_in[25];
  const float* g2w = (const float*)d_in[26]; const float* g2b = (const float*)d_in[27];
  const float* g2g = (const float*)d_in[28]; const float* g2be = (const float*)d_in[29];
  const float* g2m = (const float*)d_in[30]; const float* g2v = (const float*)d_in[31];
  const float* fw1 = (const float*)d_in[32]; const float* fb1 = (const float*)d_in[33];
  const float* fw2 = (const float*)d_in[34]; const float* fb2 = (const float*)d_in[35];

  char* ws = (char*)d_ws;
  bf16*  W1f   = (bf16*)(ws + 0);          // 512*1088 bf16  = 1,114,112 B
  bf16*  W2f   = (bf16*)(ws + 1114112);    // 1024*512 bf16  = 1,048,576 B
  bf16*  CWf   = (bf16*)(ws + 2162688);    // 1024*64  bf16  =   131,072 B
  bf16*  F1f   = (bf16*)(ws + 2293760);    // 256*2048 bf16  = 1,048,576 B
  float* b1cat = (float*)(ws + 3342336);   // 512 f32
  float* b2sum = (float*)(ws + 3344384);   // 1024 f32
  bf16*  r_ws  = (bf16*)(ws + 3407872);    // 16384*2048 bf16 = 67,108,864 B

  prep_w1main<<<2048, 256, 0, stream>>>(l1w, l1g, l1v, g1w, g1g, g1v, W1f);
  prep_w1tail<<<128, 256, 0, stream>>>(l1w, l1b, l1g, l1be, l1m, l1v,
                                       g1w, g1b, g1g, g1be, g1m, g1v, cw, cb, W1f, b1cat);
  prep_w2<<<2048, 256, 0, stream>>>(l2w, l2b, l2g, l2be, l2m, l2v,
                                    g2w, g2b, g2g, g2be, g2m, g2v, W2f, b2sum);
  prep_cwf<<<256, 256, 0, stream>>>(cw, cb, CWf);
  prep_f1f<<<2048, 256, 0, stream>>>(fw1, F1f);

  fused_main<<<dim3(256, 2), 512, 0, stream>>>(name1, type1, coor1, name2, type2, coor2,
                                               W1f, W2f, CWf, b1cat, b2sum, r_ws);
  fused_final<<<256, 512, 0, stream>>>(r_ws, F1f, fb1, fw2, fb2, (float*)d_out);
}

// Round 4
// 347.745 us; speedup vs baseline: 1.0402x; 1.0402x over previous
//
#include <hip/hip_runtime.h>

typedef __bf16 bf16;
typedef __bf16 bf16x8 __attribute__((ext_vector_type(8)));
typedef __bf16 bf16x4 __attribute__((ext_vector_type(4)));
typedef __bf16 bf16x2 __attribute__((ext_vector_type(2)));
typedef float  f32x4  __attribute__((ext_vector_type(4)));

#define BN_EPS 1e-5f

// Fragment-linear offset for MFMA B-operand matrix [N][K] (16x16x32 tiles):
// tile = (k/32)*ntiles + n/16 ; within tile: lane = ((k%32)/8)*16 + n%16, elem = k%8
__device__ __host__ __forceinline__ size_t frag_off(int n, int k, int ntiles) {
  return ((size_t)((k >> 5) * ntiles + (n >> 4)) << 9)
       + (size_t)((((k >> 3) & 3) << 4) + (n & 15)) * 8 + (k & 7);
}

// ---------------- prep kernels ----------------

__global__ void prep_w1main(const float* __restrict__ l1w, const float* __restrict__ l1g, const float* __restrict__ l1v,
                            const float* __restrict__ g1w, const float* __restrict__ g1g, const float* __restrict__ g1v,
                            bf16* __restrict__ W1f) {
  int gid = blockIdx.x * blockDim.x + threadIdx.x;   // 512*1024
  int n = gid >> 10, k = gid & 1023;
  float s, w;
  if (n < 256) { s = l1g[n] * rsqrtf(l1v[n] + BN_EPS); w = l1w[(size_t)n * 1024 + k]; }
  else { int nn = n - 256; s = g1g[nn] * rsqrtf(g1v[nn] + BN_EPS); w = g1w[(size_t)nn * 1024 + k]; }
  W1f[frag_off(n, k, 32)] = (bf16)(w * s);
}

// tail columns 1024..1087 of W1cat = (s*W1) @ [cw | cb | 0], plus b1cat.
// one block per n; 512 thr = 64 kc-slots x 8 j-stripes; LDS reduce.
__global__ __launch_bounds__(512)
void prep_w1tail(const float* __restrict__ l1w, const float* __restrict__ l1b, const float* __restrict__ l1g,
                 const float* __restrict__ l1be, const float* __restrict__ l1m, const float* __restrict__ l1v,
                 const float* __restrict__ g1w, const float* __restrict__ g1b, const float* __restrict__ g1g,
                 const float* __restrict__ g1be, const float* __restrict__ g1m, const float* __restrict__ g1v,
                 const float* __restrict__ cw, const float* __restrict__ cb,
                 bf16* __restrict__ W1f, float* __restrict__ b1cat) {
  int n = blockIdx.x;
  int kc = threadIdx.x & 63, js = threadIdx.x >> 6;
  const float* wrow; float s, bb, mm, be;
  if (n < 256) { s = l1g[n] * rsqrtf(l1v[n] + BN_EPS); wrow = l1w + (size_t)n * 1024;
                 bb = l1b[n]; mm = l1m[n]; be = l1be[n]; }
  else { int nn = n - 256; s = g1g[nn] * rsqrtf(g1v[nn] + BN_EPS); wrow = g1w + (size_t)nn * 1024;
         bb = g1b[nn]; mm = g1m[nn]; be = g1be[nn]; }
  float a = 0.f;
  if (kc < 49) {
    #pragma unroll 4
    for (int jj = 0; jj < 128; ++jj) {
      int j = js * 128 + jj;
      float cv = (kc < 48) ? cw[(size_t)j * 48 + kc] : cb[j];
      a += wrow[j] * cv;
    }
  }
  __shared__ float red[8][64];
  red[js][kc] = a;
  __syncthreads();
  if (threadIdx.x < 64) {
    float v = 0.f;
    #pragma unroll
    for (int r = 0; r < 8; ++r) v += red[r][threadIdx.x];
    W1f[frag_off(n, 1024 + threadIdx.x, 32)] = (bf16)((threadIdx.x < 49) ? v * s : 0.f);
  }
  if (threadIdx.x == 0) b1cat[n] = s * (bb - mm) + be;
}

__global__ void prep_w2(const float* __restrict__ l2w, const float* __restrict__ l2b, const float* __restrict__ l2g,
                        const float* __restrict__ l2be, const float* __restrict__ l2m, const float* __restrict__ l2v,
                        const float* __restrict__ g2w, const float* __restrict__ g2b, const float* __restrict__ g2g,
                        const float* __restrict__ g2be, const float* __restrict__ g2m, const float* __restrict__ g2v,
                        bf16* __restrict__ W2f, float* __restrict__ b2sum) {
  int gid = blockIdx.x * blockDim.x + threadIdx.x;   // 1024*512
  int n = gid >> 9, k = gid & 511;
  float w;
  if (k < 256) { float s = l2g[n] * rsqrtf(l2v[n] + BN_EPS); w = l2w[(size_t)n * 256 + k] * s; }
  else { float s = g2g[n] * rsqrtf(g2v[n] + BN_EPS); w = g2w[(size_t)n * 256 + (k - 256)] * s; }
  W2f[frag_off(n, k, 64)] = (bf16)w;
  if (k == 0) {
    float sl = l2g[n] * rsqrtf(l2v[n] + BN_EPS), sg = g2g[n] * rsqrtf(g2v[n] + BN_EPS);
    b2sum[n] = sl * (l2b[n] - l2m[n]) + l2be[n] + sg * (g2b[n] - g2m[n]) + g2be[n];
  }
}

__global__ void prep_cwf(const float* __restrict__ cw, const float* __restrict__ cb, bf16* __restrict__ CWf) {
  int gid = blockIdx.x * blockDim.x + threadIdx.x;   // 1024*64
  int n = gid >> 6, kc = gid & 63;
  float v = (kc < 48) ? cw[(size_t)n * 48 + kc] : (kc == 48 ? cb[n] : 0.f);
  CWf[frag_off(n, kc, 64)] = (bf16)v;
}

__global__ void prep_f1f(const float* __restrict__ fw1, bf16* __restrict__ F1f) {
  int gid = blockIdx.x * blockDim.x + threadIdx.x;   // 256*2048
  int n = gid >> 11, k = gid & 2047;
  F1f[frag_off(n, k, 16)] = (bf16)fw1[(size_t)n * 2048 + k];
}

// ---------------- main fused kernel: M=32, 2 blocks/CU, pipelined GEMM1 -> GEMM2 -> combine ----------------

__global__ __launch_bounds__(512, 4)
void fused_main(const float* __restrict__ name1, const float* __restrict__ type1, const float* __restrict__ coor1,
                const float* __restrict__ name2, const float* __restrict__ type2, const float* __restrict__ coor2,
                const bf16* __restrict__ W1f, const bf16* __restrict__ W2f, const bf16* __restrict__ CWf,
                const float* __restrict__ b1cat, const float* __restrict__ b2sum,
                bf16* __restrict__ r_ws) {
  const int t = blockIdx.y;
  const float* __restrict__ name = t ? name2 : name1;
  const float* __restrict__ typ  = t ? type2 : type1;
  const float* __restrict__ coor = t ? coor2 : coor1;
  const int b0 = blockIdx.x * 32;
  const int tid = threadIdx.x;
  const int lane = tid & 63;
  const int wv = tid >> 6;          // 0..7
  const int arow = lane & 15;
  const int q    = lane >> 4;
  const int kgrp = q << 3;

  __shared__ bf16 A4[4][32][40];    // 4 rotating 32-k chunk regions, 10,240 B
  __shared__ bf16 Hs[32][520];      // relu(GEMM1) [hL|hG], 33,280 B
  __shared__ bf16 Rp[32][264];      // r pack buffer per n-chunk, 16,896 B   (total 60,416 B -> 2 blocks/CU)

  const int srow = tid >> 4;        // 0..31
  const int sc2  = (tid & 15) * 2;  // 0,2,..,30

  // ---- GEMM1: 34 chunks of 32 k (32 from name+typ, 2 tail from [coor|1|0]); depth-3 prefetch ----
  float2 fn[3], ft[3];
  auto LOADC = [&](int j, int s) {
    if (j < 32) {
      fn[s] = *reinterpret_cast<const float2*>(name + (size_t)(b0 + srow) * 1024 + j * 32 + sc2);
      ft[s] = *reinterpret_cast<const float2*>(typ  + (size_t)(b0 + srow) * 1024 + j * 32 + sc2);
    } else {
      int c0 = (j - 32) * 32 + sc2;
      float v0 = (c0 < 48) ? coor[(size_t)(b0 + srow) * 48 + c0] : (c0 == 48 ? 1.f : 0.f);
      int c1 = c0 + 1;
      float v1 = (c1 < 48) ? coor[(size_t)(b0 + srow) * 48 + c1] : (c1 == 48 ? 1.f : 0.f);
      fn[s] = make_float2(v0, v1);
      ft[s] = make_float2(0.f, 0.f);
    }
  };
  auto WRITEC = [&](int j, int s) {
    bf16x2 e;
    e[0] = (bf16)(fn[s].x + ft[s].x);
    e[1] = (bf16)(fn[s].y + ft[s].y);
    *reinterpret_cast<bf16x2*>(&A4[j & 3][srow][sc2]) = e;
    if (j < 32)   // e round-trip: store bf16 e to r_ws (r overwrites later)
      *reinterpret_cast<bf16x2*>(r_ws + (size_t)(b0 + srow) * 2048 + (size_t)t * 1024 + j * 32 + sc2) = e;
  };

  LOADC(0, 0); LOADC(1, 1); LOADC(2, 2);

  f32x4 acc1[2][4] = {};
  #pragma unroll 1
  for (int j = 0; j < 34; ++j) {
    int s = j % 3;
    WRITEC(j, s);
    if (j + 3 < 34) LOADC(j + 3, s);
    __builtin_amdgcn_sched_barrier(0);
    asm volatile("s_waitcnt lgkmcnt(0)" ::: "memory");
    __builtin_amdgcn_s_barrier();
    __builtin_amdgcn_sched_barrier(0);
    bf16x8 a0 = *reinterpret_cast<const bf16x8*>(&A4[j & 3][arow][kgrp]);
    bf16x8 a1 = *reinterpret_cast<const bf16x8*>(&A4[j & 3][16 + arow][kgrp]);
    #pragma unroll
    for (int u = 0; u < 4; ++u) {
      bf16x8 b = *reinterpret_cast<const bf16x8*>(W1f + (((size_t)(j * 32 + wv * 4 + u)) << 9) + lane * 8);
      acc1[0][u] = __builtin_amdgcn_mfma_f32_16x16x32_bf16(a0, b, acc1[0][u], 0, 0, 0);
      acc1[1][u] = __builtin_amdgcn_mfma_f32_16x16x32_bf16(a1, b, acc1[1][u], 0, 0, 0);
    }
  }
  __syncthreads();   // full barrier: drains e-stores (vmcnt 0) + protects A4[0..1] reuse as c-operands

  // ---- H = relu(GEMM1 + b1cat) ----
  #pragma unroll
  for (int u = 0; u < 4; ++u) {
    int col = (wv * 4 + u) * 16 + arow;
    float bb = b1cat[col];
    #pragma unroll
    for (int m = 0; m < 2; ++m) {
      #pragma unroll
      for (int i = 0; i < 4; ++i) {
        int row = m * 16 + q * 4 + i;
        Hs[row][col] = (bf16)fmaxf(acc1[m][u][i] + bb, 0.f);
      }
    }
  }
  __syncthreads();

  // ---- GEMM2 + combine, 4 n-chunks of 256 cols; c from A4[0..1] (coor tail still resident) ----
  #pragma unroll 1
  for (int nc = 0; nc < 4; ++nc) {
    f32x4 acc2[2][2] = {}, cacc[2][2] = {};
    #pragma unroll 4
    for (int ks = 0; ks < 16; ++ks) {
      bf16x8 a0 = *reinterpret_cast<const bf16x8*>(&Hs[arow][ks * 32 + kgrp]);
      bf16x8 a1 = *reinterpret_cast<const bf16x8*>(&Hs[16 + arow][ks * 32 + kgrp]);
      #pragma unroll
      for (int uu = 0; uu < 2; ++uu) {
        bf16x8 b = *reinterpret_cast<const bf16x8*>(W2f + (((size_t)(ks * 64 + nc * 16 + wv * 2 + uu)) << 9) + lane * 8);
        acc2[0][uu] = __builtin_amdgcn_mfma_f32_16x16x32_bf16(a0, b, acc2[0][uu], 0, 0, 0);
        acc2[1][uu] = __builtin_amdgcn_mfma_f32_16x16x32_bf16(a1, b, acc2[1][uu], 0, 0, 0);
      }
    }
    #pragma unroll
    for (int jj = 0; jj < 2; ++jj) {
      bf16x8 a0 = *reinterpret_cast<const bf16x8*>(&A4[jj][arow][kgrp]);
      bf16x8 a1 = *reinterpret_cast<const bf16x8*>(&A4[jj][16 + arow][kgrp]);
      #pragma unroll
      for (int uu = 0; uu < 2; ++uu) {
        bf16x8 b = *reinterpret_cast<const bf16x8*>(CWf + (((size_t)(jj * 64 + nc * 16 + wv * 2 + uu)) << 9) + lane * 8);
        cacc[0][uu] = __builtin_amdgcn_mfma_f32_16x16x32_bf16(a0, b, cacc[0][uu], 0, 0, 0);
        cacc[1][uu] = __builtin_amdgcn_mfma_f32_16x16x32_bf16(a1, b, cacc[1][uu], 0, 0, 0);
      }
    }
    // combine: wei = sigmoid(x), r = 2e + 2*wei*(c-e); e read back from r_ws (bf16)
    #pragma unroll
    for (int uu = 0; uu < 2; ++uu) {
      int colg = (wv * 2 + uu) * 16 + arow;
      int col = nc * 256 + colg;
      float b2 = b2sum[col];
      #pragma unroll
      for (int m = 0; m < 2; ++m) {
        #pragma unroll
        for (int i = 0; i < 4; ++i) {
          int row = m * 16 + q * 4 + i;
          float x = acc2[m][uu][i] + b2;
          float wei = 1.f / (1.f + __expf(-x));
          float e = (float)r_ws[(size_t)(b0 + row) * 2048 + (size_t)t * 1024 + col];
          float cv = cacc[m][uu][i];
          Rp[row][colg] = (bf16)(2.f * e + 2.f * wei * (cv - e));
        }
      }
    }
    __syncthreads();   // e-reads resolved; Rp complete
    #pragma unroll
    for (int it = 0; it < 2; ++it) {
      int idx = it * 512 + tid;
      int row = idx >> 5, cg = idx & 31;
      *reinterpret_cast<bf16x8*>(r_ws + (size_t)(b0 + row) * 2048 + (size_t)t * 1024 + nc * 256 + cg * 8) =
        *reinterpret_cast<const bf16x8*>(&Rp[row][cg * 8]);
    }
    __syncthreads();   // Rp free for next chunk
  }
}

// ---------------- final kernel: out = sigmoid(relu(r@fw1T+fb1)@fw2T+fb2), M=64, 2 blocks/CU ----------------

__global__ __launch_bounds__(512, 4)
void fused_final(const bf16* __restrict__ r_ws, const bf16* __restrict__ F1f,
                 const float* __restrict__ fb1, const float* __restrict__ fw2,
                 const float* __restrict__ fb2, float* __restrict__ out) {
  const int b0 = blockIdx.x * 64;
  const int tid = threadIdx.x;
  const int lane = tid & 63;
  const int wv = tid >> 6;
  const int arow = lane & 15;
  const int q    = lane >> 4;
  const int kgrp = q << 3;

  __shared__ bf16 RT[2][64][264];   // 67,584 B -> 2 blocks/CU
  float (*H2)[260] = reinterpret_cast<float (*)[260]>(&RT[0][0][0]);  // overlay after k-loop

  bf16x8 sv[4];
  auto SLOAD = [&](int kc) {
    #pragma unroll
    for (int g = 0; g < 4; ++g) {
      int f = g * 512 + tid;
      int row = f >> 5, colg = f & 31;
      sv[g] = *reinterpret_cast<const bf16x8*>(r_ws + (size_t)(b0 + row) * 2048 + kc * 256 + colg * 8);
    }
  };
  auto SWRITE = [&](int buf) {
    #pragma unroll
    for (int g = 0; g < 4; ++g) {
      int f = g * 512 + tid;
      int row = f >> 5, colg = f & 31;
      *reinterpret_cast<bf16x8*>(&RT[buf][row][colg * 8]) = sv[g];
    }
  };

  SLOAD(0); SWRITE(0);
  __syncthreads();

  f32x4 acc[4][2] = {};
  #pragma unroll 1
  for (int kc = 0; kc < 8; ++kc) {
    if (kc < 7) SLOAD(kc + 1);          // issue HBM loads early (T14)
    #pragma unroll
    for (int ks = 0; ks < 8; ++ks) {
      int ksg = kc * 8 + ks;
      bf16x8 a[4];
      #pragma unroll
      for (int m = 0; m < 4; ++m)
        a[m] = *reinterpret_cast<const bf16x8*>(&RT[kc & 1][m * 16 + arow][ks * 32 + kgrp]);
      #pragma unroll
      for (int u = 0; u < 2; ++u) {
        bf16x8 b = *reinterpret_cast<const bf16x8*>(F1f + (((size_t)(ksg * 16 + wv * 2 + u)) << 9) + lane * 8);
        #pragma unroll
        for (int m = 0; m < 4; ++m)
          acc[m][u] = __builtin_amdgcn_mfma_f32_16x16x32_bf16(a[m], b, acc[m][u], 0, 0, 0);
      }
    }
    if (kc < 7) SWRITE((kc + 1) & 1);   // ds_write late; loads were in flight
    __syncthreads();
  }

  #pragma unroll
  for (int u = 0; u < 2; ++u) {
    int col = (wv * 2 + u) * 16 + arow;
    float bb = fb1[col];
    #pragma unroll
    for (int m = 0; m < 4; ++m) {
      #pragma unroll
      for (int i2 = 0; i2 < 4; ++i2) {
        int row = m * 16 + q * 4 + i2;
        H2[row][col] = fmaxf(acc[m][u][i2] + bb, 0.f);
      }
    }
  }
  __syncthreads();

  int row = tid >> 3, sub = tid & 7;
  float p = 0.f;
  #pragma unroll
  for (int c = 0; c < 32; ++c) p += H2[row][sub * 32 + c] * fw2[sub * 32 + c];
  p += __shfl_xor(p, 1, 8);
  p += __shfl_xor(p, 2, 8);
  p += __shfl_xor(p, 4, 8);
  if (sub == 0) out[b0 + row] = 1.f / (1.f + __expf(-(p + fb2[0])));
}

// ---------------- launcher ----------------

extern "C" void kernel_launch(void* const* d_in, const int* in_sizes, int n_in,
                              void* d_out, int out_size, void* d_ws, size_t ws_size,
                              hipStream_t stream) {
  const float* name1 = (const float*)d_in[0];
  const float* type1 = (const float*)d_in[1];
  const float* coor1 = (const float*)d_in[2];
  const float* name2 = (const float*)d_in[3];
  const float* type2 = (const float*)d_in[4];
  const float* coor2 = (const float*)d_in[5];
  const float* cw    = (const float*)d_in[6];
  const float* cb    = (const float*)d_in[7];
  const float* l1w = (const float*)d_in[8];  const float* l1b = (const float*)d_in[9];
  const float* l1g = (const float*)d_in[10]; const float* l1be = (const float*)d_in[11];
  const float* l1m = (const float*)d_in[12]; const float* l1v = (const float*)d_in[13];
  const float* l2w = (const float*)d_in[14]; const float* l2b = (const float*)d_in[15];
  const float* l2g = (const float*)d_in[16]; const float* l2be = (const float*)d_in[17];
  const float* l2m = (const float*)d_in[18]; const float* l2v = (const float*)d_in[19];
  const float* g1w = (const float*)d_in[20]; const float* g1b = (const float*)d_in[21];
  const float* g1g = (const float*)d_in[22]; const float* g1be = (const float*)d_in[23];
  const float* g1m = (const float*)d_in[24]; const float* g1v = (const float*)d_in[25];
  const float* g2w = (const float*)d_in[26]; const float* g2b = (const float*)d_in[27];
  const float* g2g = (const float*)d_in[28]; const float* g2be = (const float*)d_in[29];
  const float* g2m = (const float*)d_in[30]; const float* g2v = (const float*)d_in[31];
  const float* fw1 = (const float*)d_in[32]; const float* fb1 = (const float*)d_in[33];
  const float* fw2 = (const float*)d_in[34]; const float* fb2 = (const float*)d_in[35];

  char* ws = (char*)d_ws;
  bf16*  W1f   = (bf16*)(ws + 0);          // 512*1088 bf16  = 1,114,112 B
  bf16*  W2f   = (bf16*)(ws + 1114112);    // 1024*512 bf16  = 1,048,576 B
  bf16*  CWf   = (bf16*)(ws + 2162688);    // 1024*64  bf16  =   131,072 B
  bf16*  F1f   = (bf16*)(ws + 2293760);    // 256*2048 bf16  = 1,048,576 B
  float* b1cat = (float*)(ws + 3342336);   // 512 f32
  float* b2sum = (float*)(ws + 3344384);   // 1024 f32
  bf16*  r_ws  = (bf16*)(ws + 3407872);    // 16384*2048 bf16 = 67,108,864 B (holds e, then r)

  prep_w1main<<<2048, 256, 0, stream>>>(l1w, l1g, l1v, g1w, g1g, g1v, W1f);
  prep_w1tail<<<512, 512, 0, stream>>>(l1w, l1b, l1g, l1be, l1m, l1v,
                                       g1w, g1b, g1g, g1be, g1m, g1v, cw, cb, W1f, b1cat);
  prep_w2<<<2048, 256, 0, stream>>>(l2w, l2b, l2g, l2be, l2m, l2v,
                                    g2w, g2b, g2g, g2be, g2m, g2v, W2f, b2sum);
  prep_cwf<<<256, 256, 0, stream>>>(cw, cb, CWf);
  prep_f1f<<<2048, 256, 0, stream>>>(fw1, F1f);

  fused_main<<<dim3(512, 2), 512, 0, stream>>>(name1, type1, coor1, name2, type2, coor2,
                                               W1f, W2f, CWf, b1cat, b2sum, r_ws);
  fused_final<<<256, 512, 0, stream>>>(r_ws, F1f, fb1, fw2, fb2, (float*)d_out);
}